// Round 4
// baseline (102428.406 us; speedup 1.0000x reference)
//
#include <hip/hip_runtime.h>

#define BB 256
#define SS 128
#define FDIM 128
#define HH 512
#define H4 2048
#define TDEC 128
#define SOS_TOK 128
#define NWG 256
#define SLOT 131072   // 256*512 floats

typedef short short8 __attribute__((ext_vector_type(8)));
typedef float f32x4 __attribute__((ext_vector_type(4)));
typedef unsigned short ushort_t;

__device__ __forceinline__ float sigf(float x){ return 1.0f/(1.0f+__expf(-x)); }
__device__ __forceinline__ float tanh_f(float x){ return 1.0f - 2.0f/(__expf(2.0f*x)+1.0f); }

// round-to-nearest-even bf16 2-way split: x ~= hi + mid
__device__ __forceinline__ void split2(float x, unsigned& h, unsigned& m){
    union { float f; unsigned u; } a; a.f = x;
    h = (a.u + 0x7fffu + ((a.u>>16)&1u)) >> 16;
    union { unsigned u; float f; } hf; hf.u = h << 16;
    float r1 = x - hf.f;
    union { float f; unsigned u; } b; b.f = r1;
    m = (b.u + 0x7fffu + ((b.u>>16)&1u)) >> 16;
}

__device__ __forceinline__ void splitw8(float4 v, uint2& H, uint2& M){
    unsigned h0,m0,h1,m1,h2,m2,h3,m3;
    split2(v.x,h0,m0); split2(v.y,h1,m1); split2(v.z,h2,m2); split2(v.w,h3,m3);
    H.x = h0 | (h1<<16); H.y = h2 | (h3<<16);
    M.x = m0 | (m1<<16); M.y = m2 | (m3<<16);
}

// weight split: fp32 [N][K] (opt gate-interleave, opt 2-src K-concat) -> 2 bf16 planes
// k-panel layout [K/32][N][32] with 16B-part XOR swizzle
__global__ void split_w(const float* __restrict__ srcA, int KA,
                        const float* __restrict__ srcB, int KB, int ilv,
                        ushort_t* __restrict__ ph, ushort_t* __restrict__ pm, int N){
    int k = blockIdx.x*128 + threadIdx.x;
    int n = blockIdx.y;
    int K = KA + KB;
    if (k >= K) return;
    int row = ilv ? ((n&3)*512 + (n>>2)) : n;
    float w = (k < KA) ? srcA[(size_t)row*KA + k] : srcB[(size_t)row*KB + (k-KA)];
    unsigned h,m; split2(w,h,m);
    size_t off = (size_t)(k>>5)*((size_t)N*32) + (size_t)n*32
               + ((((k>>3)&3) ^ (n&3))<<3) + (k&7);
    ph[off]=(ushort_t)h; pm[off]=(ushort_t)m;
}

__global__ void repack_b(float* __restrict__ dst, const float* __restrict__ src){
    int id = blockIdx.x*256 + threadIdx.x;
    if (id >= 2048) return;
    int g = id & 3, q = id >> 2;
    dst[id] = src[g*512 + q];
}

__global__ void init_misc(int* bar){ if (threadIdx.x < 2) bar[threadIdx.x] = 0; }

// ---- device-wide barrier (256 WGs, 1/CU co-resident) ----
__device__ __forceinline__ void gbar(int* bar){
    __syncthreads();
    if (threadIdx.x == 0){
        __threadfence();
        int g = __hip_atomic_load(&bar[1], __ATOMIC_RELAXED, __HIP_MEMORY_SCOPE_AGENT);
        int a = __hip_atomic_fetch_add(&bar[0], 1, __ATOMIC_ACQ_REL, __HIP_MEMORY_SCOPE_AGENT);
        if (a == NWG-1){
            __hip_atomic_store(&bar[0], 0, __ATOMIC_RELAXED, __HIP_MEMORY_SCOPE_AGENT);
            __hip_atomic_fetch_add(&bar[1], 1, __ATOMIC_ACQ_REL, __HIP_MEMORY_SCOPE_AGENT);
        } else {
            while (__hip_atomic_load(&bar[1], __ATOMIC_ACQUIRE, __HIP_MEMORY_SCOPE_AGENT) == g)
                __builtin_amdgcn_s_sleep(8);
        }
        __threadfence();
    }
    __syncthreads();
}

// ---- 64x64 GEMM tile, fp32 via 2-way bf16 split (3 MFMA products) ----
// A: fp32, up to 3 K-segments: [A0 (strides a0B/a0T or tok-indirect) | A1 | A2], seg1/2 stride 512
// W: 2 prebuilt bf16 planes [K/32][Nld][32] swizzled
// mode 0: out = acc + bias (+relu); mode 2: fused LSTM cell (gate-interleaved cols)
__device__ __forceinline__ void gtile(
    ushort_t (&sA)[2][2][2048], ushort_t (&sW)[2][2][2048],
    int row0, int col0,
    const float* __restrict__ A0, long a0B, long a0T,
    const float* __restrict__ A1, const float* __restrict__ A2,
    const int* __restrict__ tok,
    int kx1, int kx2, int Kc,
    const ushort_t* __restrict__ Wh, const ushort_t* __restrict__ Wm, int Nld,
    const float* __restrict__ bias, int relu, int mode,
    float* __restrict__ out, long oB, long oT,
    float* __restrict__ c_io, float* __restrict__ seqo)
{
    const int tid = threadIdx.x;
    const int nk = Kc >> 5;
    f32x4 acc[2][2];
    acc[0][0]=(f32x4){0.f,0.f,0.f,0.f}; acc[0][1]=(f32x4){0.f,0.f,0.f,0.f};
    acc[1][0]=(f32x4){0.f,0.f,0.f,0.f}; acc[1][1]=(f32x4){0.f,0.f,0.f,0.f};
    const int sr = tid >> 2, q4 = tid & 3;
    const int gr = row0 + sr;
    long ro0;
    if (tok) ro0 = (long)tok[gr & 255] * a0B;
    else     ro0 = (long)(gr & 255)*a0B + (long)(gr >> 8)*a0T;
    const long roh = (long)gr * 512;
    const size_t wbase = (size_t)col0*32 + (size_t)tid*8;
    const int swz = sr & 3;
    const int b0 = sr*32 + (q4 & 1)*4;
    const int p0s = ((q4>>1) ^ swz) << 3;
    const int p1s = ((2 + (q4>>1)) ^ swz) << 3;
    float4 va0, va1; uint4 vw0, vw1;

    auto issue = [&](int kt){
        int kg = kt*32;
        const float* sp; long ro; int kb;
        if (kg < kx1){ sp=A0; ro=ro0; kb=kg; }
        else if (kg < kx2){ sp=A1; ro=roh; kb=kg-kx1; }
        else { sp=A2; ro=roh; kb=kg-kx2; }
        const float* p = sp + ro + kb + q4*4;
        va0 = *(const float4*)p;
        va1 = *(const float4*)(p + 16);
        size_t wi = (size_t)kt*((size_t)Nld*32) + wbase;
        vw0 = *(const uint4*)(Wh + wi);
        vw1 = *(const uint4*)(Wm + wi);
    };
    auto commit = [&](int buf){
        uint2 H,M;
        splitw8(va0,H,M);
        *(uint2*)&sA[buf][0][b0 + p0s] = H;
        *(uint2*)&sA[buf][1][b0 + p0s] = M;
        splitw8(va1,H,M);
        *(uint2*)&sA[buf][0][b0 + p1s] = H;
        *(uint2*)&sA[buf][1][b0 + p1s] = M;
        *(uint4*)&sW[buf][0][tid*8] = vw0;
        *(uint4*)&sW[buf][1][tid*8] = vw1;
    };

    const int wid = tid >> 6, lane = tid & 63;
    const int wy = wid >> 1, wx = wid & 1;
    const int l15 = lane & 15, l4 = lane >> 4;
    const int offA = (wy*32 + l15)*32 + ((l4 ^ (l15&3))<<3);
    const int offB = (wx*32 + l15)*32 + ((l4 ^ (l15&3))<<3);

    auto compute = [&](int buf){
        short8 a0h = *(const short8*)&sA[buf][0][offA];
        short8 a0m = *(const short8*)&sA[buf][1][offA];
        short8 a1h = *(const short8*)&sA[buf][0][offA+512];
        short8 a1m = *(const short8*)&sA[buf][1][offA+512];
        short8 b0h = *(const short8*)&sW[buf][0][offB];
        short8 b0m = *(const short8*)&sW[buf][1][offB];
        short8 b1h = *(const short8*)&sW[buf][0][offB+512];
        short8 b1m = *(const short8*)&sW[buf][1][offB+512];
        acc[0][0] = __builtin_amdgcn_mfma_f32_16x16x32_bf16(a0h,b0h,acc[0][0],0,0,0);
        acc[0][0] = __builtin_amdgcn_mfma_f32_16x16x32_bf16(a0h,b0m,acc[0][0],0,0,0);
        acc[0][0] = __builtin_amdgcn_mfma_f32_16x16x32_bf16(a0m,b0h,acc[0][0],0,0,0);
        acc[0][1] = __builtin_amdgcn_mfma_f32_16x16x32_bf16(a0h,b1h,acc[0][1],0,0,0);
        acc[0][1] = __builtin_amdgcn_mfma_f32_16x16x32_bf16(a0h,b1m,acc[0][1],0,0,0);
        acc[0][1] = __builtin_amdgcn_mfma_f32_16x16x32_bf16(a0m,b1h,acc[0][1],0,0,0);
        acc[1][0] = __builtin_amdgcn_mfma_f32_16x16x32_bf16(a1h,b0h,acc[1][0],0,0,0);
        acc[1][0] = __builtin_amdgcn_mfma_f32_16x16x32_bf16(a1h,b0m,acc[1][0],0,0,0);
        acc[1][0] = __builtin_amdgcn_mfma_f32_16x16x32_bf16(a1m,b0h,acc[1][0],0,0,0);
        acc[1][1] = __builtin_amdgcn_mfma_f32_16x16x32_bf16(a1h,b1h,acc[1][1],0,0,0);
        acc[1][1] = __builtin_amdgcn_mfma_f32_16x16x32_bf16(a1h,b1m,acc[1][1],0,0,0);
        acc[1][1] = __builtin_amdgcn_mfma_f32_16x16x32_bf16(a1m,b1h,acc[1][1],0,0,0);
    };

    issue(0);
    commit(0);
    __syncthreads();
    int buf = 0;
    for (int kt=0; kt<nk; ++kt){
        bool more = (kt+1 < nk);
        if (more) issue(kt+1);
        compute(buf);
        if (more) commit(buf^1);
        __syncthreads();
        buf ^= 1;
    }

    if (mode == 0){
        #pragma unroll
        for (int fa=0; fa<2; fa++){
            #pragma unroll
            for (int fb=0; fb<2; fb++){
                int gc = col0 + wx*32 + fb*16 + l15;
                float bv = bias ? bias[gc] : 0.0f;
                #pragma unroll
                for (int i=0;i<4;i++){
                    int r = row0 + wy*32 + fa*16 + l4*4 + i;
                    float v = acc[fa][fb][i] + bv;
                    if (relu) v = fmaxf(v, 0.0f);
                    out[(size_t)(r&255)*oB + (size_t)(r>>8)*oT + gc] = v;
                }
            }
        }
    } else {
        #pragma unroll
        for (int fa=0; fa<2; fa++){
            #pragma unroll
            for (int fb=0; fb<2; fb++){
                int gc = col0 + wx*32 + fb*16 + l15;
                int q = gc >> 2, g = gc & 3;
                float ab = bias[gc];
                #pragma unroll
                for (int i=0;i<4;i++){
                    int r = row0 + wy*32 + fa*16 + l4*4 + i;
                    float z = acc[fa][fb][i] + ab;
                    float x1 = __shfl_xor(z, 1);
                    float x2 = __shfl_xor(z, 2);
                    float x3 = __shfl_xor(z, 3);
                    float zi = (g==0)?z :(g==1)?x1:(g==2)?x2:x3;
                    float zf = (g==1)?z :(g==0)?x1:(g==3)?x2:x3;
                    float zg = (g==2)?z :(g==3)?x1:(g==0)?x2:x3;
                    float zo = (g==3)?z :(g==2)?x1:(g==1)?x2:x3;
                    float co = c_io[(size_t)r*512 + q];
                    float cn = sigf(zf)*co + sigf(zi)*tanh_f(zg);
                    float hn = sigf(zo)*tanh_f(cn);
                    if (g == 1) c_io[(size_t)r*512 + q] = cn;
                    else if (g == 0) seqo[(size_t)r*512 + q] = hn;
                }
            }
        }
    }
}

// ordinary GEMM kernel (used for ot = enc_outs @ fc2^T + b)
__global__ __launch_bounds__(256) void gk(
    const float* __restrict__ A0, long a0B, long a0T,
    const ushort_t* __restrict__ Wh, const ushort_t* __restrict__ Wm, int Nld, int Kc,
    const float* __restrict__ bias, float* __restrict__ out, long oB, long oT)
{
    __shared__ __align__(16) ushort_t sA[2][2][2048];
    __shared__ __align__(16) ushort_t sW[2][2][2048];
    gtile(sA, sW, blockIdx.y*64, blockIdx.x*64,
          A0, a0B, a0T, nullptr, nullptr, nullptr,
          Kc, Kc, Kc, Wh, Wm, Nld, bias, 0, 0, out, oB, oT, nullptr, nullptr);
}

// ---------------- persistent encoder: 3 layers pipelined across steps ----------------
struct EncArgs {
    const float* l2;
    const ushort_t* Wh[3]; const ushort_t* Wm[3];
    const float* bias[3];
    float* bufraw; float* cst; int* bar;
};

__global__ __launch_bounds__(256) void enc_persist(EncArgs P){
    __shared__ __align__(16) ushort_t sA[2][2][2048];
    __shared__ __align__(16) ushort_t sW[2][2][2048];
    const int wg = blockIdx.x, tid = threadIdx.x;
    // zero slots -1..1 and c-states
    {
        float4 z = {0.f,0.f,0.f,0.f};
        int id = wg*256 + tid;
        float4* b4 = (float4*)P.bufraw;
        float4* c4 = (float4*)P.cst;
        for (int i=id; i<3*SLOT/4; i+=65536){ b4[i] = z; c4[i] = z; }
    }
    gbar(P.bar);
    for (int tau=0; tau<130; ++tau){
        int lmin = (tau > 127) ? (tau - 127) : 0;
        int lmax = (tau < 2) ? tau : 2;
        int ntask = (lmax - lmin + 1) * 128;
        for (int task = wg; task < ntask; task += NWG){
            int l = lmin + (task >> 7);
            int s = tau - l;
            int tt = task & 127;
            int row0 = (tt & 3)*64, col0 = (tt >> 2)*64;
            const float* A0; long a0B; int kx1, Kc;
            if (l == 0){ A0 = P.l2 + (size_t)s*FDIM; a0B = (long)SS*FDIM; kx1 = 128; Kc = 640; }
            else { A0 = P.bufraw + (size_t)(s+3-l+1)*SLOT; a0B = 512; kx1 = 512; Kc = 1024; }
            const float* A1 = P.bufraw + (size_t)(s+1-l+1)*SLOT;   // h_prev
            float* seqo = P.bufraw + (size_t)(s+2-l+1)*SLOT;       // h_out
            float* cio = P.cst + (size_t)l*SLOT;
            gtile(sA, sW, row0, col0,
                  A0, a0B, 0L, A1, nullptr, nullptr,
                  kx1, Kc, Kc,
                  P.Wh[l], P.Wm[l], 2048,
                  P.bias[l], 0, 2,
                  nullptr, 0L, 0L, cio, seqo);
        }
        gbar(P.bar);
    }
}

// ---------------- persistent decoder ----------------
struct DecArgs {
    const float* emb; const float* fc3;
    const ushort_t* Wh[7]; const ushort_t* Wm[7];   // dec0,dec1,dec2,fc1,w1,w2,w3
    const float* bias[7];                            // br_d0..2, fc1_b, b1, b2, b3
    float* bufraw; float* cst;
    float* h00; float* h01; float* h10; float* h11; float* h20; float* h21;
    float* ctx; float* ht; float* hdd1; float* hdd2;
    float* ot; float* outp; int* tok; int* bar;
};

__global__ __launch_bounds__(256) void dec_persist(DecArgs P){
    __shared__ __align__(16) ushort_t sA[2][2][2048];
    __shared__ __align__(16) ushort_t sW[2][2][2048];
    __shared__ float hts[256], f3s[256], wsm[SS], lgs[128];
    const int wg = blockIdx.x, tid = threadIdx.x;
    float* hp[3][2] = {{P.h00,P.h01},{P.h10,P.h11},{P.h20,P.h21}};
    const float* enc = P.bufraw + SLOT;   // slot 0 = enc_outs [s][b][512]
    // init: h[l][0] <- encoder hT (slots 129-l), ctx=0, tok=SOS
    {
        int id = wg*256 + tid;
        for (int l=0;l<3;l++){
            const float4* src = (const float4*)(P.bufraw + (size_t)(129-l+1)*SLOT);
            float4* dst = (float4*)hp[l][0];
            for (int i=id; i<SLOT/4; i+=65536) dst[i] = src[i];
        }
        float4 z = {0.f,0.f,0.f,0.f};
        float4* c4 = (float4*)P.ctx;
        for (int i=id; i<SLOT/4; i+=65536) c4[i] = z;
        if (id < 256) P.tok[id] = SOS_TOK;
    }
    gbar(P.bar);

    for (int t=0; t<TDEC; ++t){
        const int p = t & 1;
        // P1: LSTM L0  [emb[tok] | ctx | h0_prev], K=1536
        for (int task=wg; task<128; task+=NWG){
            int row0=(task&3)*64, col0=(task>>2)*64;
            gtile(sA,sW,row0,col0, P.emb,512L,0L, P.ctx, hp[0][p], P.tok,
                  512,1024,1536, P.Wh[0],P.Wm[0],2048, P.bias[0],0,2,
                  nullptr,0L,0L, P.cst, hp[0][p^1]);
        }
        gbar(P.bar);
        // P2: LSTM L1 [h0_new | h1_prev], K=1024
        for (int task=wg; task<128; task+=NWG){
            int row0=(task&3)*64, col0=(task>>2)*64;
            gtile(sA,sW,row0,col0, hp[0][p^1],512L,0L, hp[1][p], nullptr, nullptr,
                  512,1024,1024, P.Wh[1],P.Wm[1],2048, P.bias[1],0,2,
                  nullptr,0L,0L, P.cst+SLOT, hp[1][p^1]);
        }
        gbar(P.bar);
        // P3: LSTM L2
        for (int task=wg; task<128; task+=NWG){
            int row0=(task&3)*64, col0=(task>>2)*64;
            gtile(sA,sW,row0,col0, hp[1][p^1],512L,0L, hp[2][p], nullptr, nullptr,
                  512,1024,1024, P.Wh[2],P.Wm[2],2048, P.bias[2],0,2,
                  nullptr,0L,0L, P.cst+2*SLOT, hp[2][p^1]);
        }
        gbar(P.bar);
        // P4: fc1  ht = h2 @ fc1^T + b  (16 tiles)
        for (int task=wg; task<16; task+=NWG){
            int row0=(task&3)*64, col0=(task>>2)*64;
            gtile(sA,sW,row0,col0, hp[2][p^1],512L,0L, nullptr,nullptr,nullptr,
                  512,512,512, P.Wh[3],P.Wm[3],256, P.bias[3],0,0,
                  P.ht,256L,0L, nullptr,nullptr);
        }
        gbar(P.bar);
        // P5: attention -> ctx (WG = batch)
        {
            int b = wg;
            hts[tid] = P.ht[(size_t)b*256 + tid];
            f3s[tid] = P.fc3[tid];
            __syncthreads();
            int wave = tid >> 6, lane = tid & 63;
            const float* otb = P.ot + (size_t)b*SS*256;
            for (int i=0;i<32;i++){
                int s = wave*32 + i;
                float4 o = *(const float4*)&otb[(size_t)s*256 + lane*4];
                int d0 = lane*4;
                float v = f3s[d0+0]*tanh_f(o.x + hts[d0+0])
                        + f3s[d0+1]*tanh_f(o.y + hts[d0+1])
                        + f3s[d0+2]*tanh_f(o.z + hts[d0+2])
                        + f3s[d0+3]*tanh_f(o.w + hts[d0+3]);
                #pragma unroll
                for (int off=32; off; off>>=1) v += __shfl_xor(v, off);
                if (lane == 0) wsm[s] = v;
            }
            __syncthreads();
            if (tid < 64){
                float v0 = wsm[tid], v1 = wsm[tid+64];
                float m = fmaxf(v0, v1);
                #pragma unroll
                for (int off=32; off; off>>=1) m = fmaxf(m, __shfl_xor(m, off));
                float e0 = __expf(v0 - m), e1 = __expf(v1 - m);
                float ss = e0 + e1;
                #pragma unroll
                for (int off=32; off; off>>=1) ss += __shfl_xor(ss, off);
                float inv = 1.0f/ss;
                wsm[tid] = e0*inv; wsm[tid+64] = e1*inv;
            }
            __syncthreads();
            float a0=0.f, a1=0.f;
            const float* eb = enc + (size_t)b*HH;
            #pragma unroll 8
            for (int s=0;s<SS;s++){
                float w = wsm[s];
                const float* e = eb + (size_t)s*BB*HH;
                a0 = fmaf(w, e[tid],     a0);
                a1 = fmaf(w, e[tid+256], a1);
            }
            P.ctx[(size_t)b*HH + tid]     = a0;
            P.ctx[(size_t)b*HH + tid+256] = a1;
        }
        gbar(P.bar);
        // P6: mlp1 [h2|ctx] @ w1^T + b1, relu (32 tiles)
        for (int task=wg; task<32; task+=NWG){
            int row0=(task&3)*64, col0=(task>>2)*64;
            gtile(sA,sW,row0,col0, hp[2][p^1],512L,0L, P.ctx, nullptr, nullptr,
                  512,1024,1024, P.Wh[4],P.Wm[4],512, P.bias[4],1,0,
                  P.hdd1,512L,0L, nullptr,nullptr);
        }
        gbar(P.bar);
        // P7: mlp2 (16 tiles)
        for (int task=wg; task<16; task+=NWG){
            int row0=(task&3)*64, col0=(task>>2)*64;
            gtile(sA,sW,row0,col0, P.hdd1,512L,0L, nullptr,nullptr,nullptr,
                  512,512,512, P.Wh[5],P.Wm[5],256, P.bias[5],1,0,
                  P.hdd2,256L,0L, nullptr,nullptr);
        }
        gbar(P.bar);
        // P8: mlp3 -> logits (8 tiles)
        float* lgp = P.outp + (size_t)t*BB*128;
        for (int task=wg; task<8; task+=NWG){
            int row0=(task&3)*64, col0=(task>>2)*64;
            gtile(sA,sW,row0,col0, P.hdd2,256L,0L, nullptr,nullptr,nullptr,
                  256,256,256, P.Wh[6],P.Wm[6],128, P.bias[6],0,0,
                  lgp,128L,0L, nullptr,nullptr);
        }
        gbar(P.bar);
        // P9: argmax (WGs 0..63, one wave per row)
        if (wg < 64){
            int r = wg*4 + (tid>>6), lane = tid & 63;
            const float* lr_ = lgp + (size_t)r*128;
            float v0 = lr_[lane], v1 = lr_[lane+64];
            float bv; int bi;
            if (v1 > v0){ bv=v1; bi=lane+64; } else { bv=v0; bi=lane; }
            #pragma unroll
            for (int off=32; off; off>>=1){
                float ov = __shfl_xor(bv, off);
                int   oi = __shfl_xor(bi, off);
                if (ov > bv || (ov == bv && oi < bi)){ bv=ov; bi=oi; }
            }
            if (lane == 0) P.tok[r] = bi;
        }
        gbar(P.bar);
        (void)lgs;
    }
}

extern "C" void kernel_launch(void* const* d_in, const int* in_sizes, int n_in,
                              void* d_out, int out_size, void* d_ws, size_t ws_size,
                              hipStream_t stream)
{
    (void)in_sizes; (void)n_in; (void)out_size; (void)ws_size;
    const float* l2      = (const float*)d_in[0];
    const float* e_wih[3] = {(const float*)d_in[1],(const float*)d_in[4],(const float*)d_in[7]};
    const float* e_whh[3] = {(const float*)d_in[2],(const float*)d_in[5],(const float*)d_in[8]};
    const float* e_b[3]   = {(const float*)d_in[3],(const float*)d_in[6],(const float*)d_in[9]};
    const float* d_wih[3] = {(const float*)d_in[10],(const float*)d_in[13],(const float*)d_in[16]};
    const float* d_whh[3] = {(const float*)d_in[11],(const float*)d_in[14],(const float*)d_in[17]};
    const float* d_b[3]   = {(const float*)d_in[12],(const float*)d_in[15],(const float*)d_in[18]};
    const float* emb   = (const float*)d_in[19];
    const float* fc1_w = (const float*)d_in[20]; const float* fc1_b = (const float*)d_in[21];
    const float* fc2_w = (const float*)d_in[22]; const float* fc2_b = (const float*)d_in[23];
    const float* fc3_w = (const float*)d_in[24];
    const float* w1 = (const float*)d_in[25]; const float* b1 = (const float*)d_in[26];
    const float* w2 = (const float*)d_in[27]; const float* b2 = (const float*)d_in[28];
    const float* w3 = (const float*)d_in[29]; const float* b3 = (const float*)d_in[30];
    float* out = (float*)d_out;

    float* base = (float*)d_ws;
    size_t off = 0;
    auto alloc = [&](size_t n)->float*{ float* r = base + off; off = (off + n + 63) & ~(size_t)63; return r; };

    // weight specs: enc0,enc1,enc2 ([x|h] concat), dec0,dec1,dec2, fc1, fc2, w1, w2, w3
    struct WSpec { const float* a; int ka; const float* b; int kb; int ilv; int n; };
    WSpec ws[11] = {
        {e_wih[0],128, e_whh[0],512, 1,2048},
        {e_wih[1],512, e_whh[1],512, 1,2048},
        {e_wih[2],512, e_whh[2],512, 1,2048},
        {d_wih[0],1024, d_whh[0],512, 1,2048},
        {d_wih[1],512, d_whh[1],512, 1,2048},
        {d_wih[2],512, d_whh[2],512, 1,2048},
        {fc1_w,512, nullptr,0, 0,256},
        {fc2_w,512, nullptr,0, 0,256},
        {w1,1024, nullptr,0, 0,512},
        {w2,512, nullptr,0, 0,256},
        {w3,256, nullptr,0, 0,128}
    };
    ushort_t* wp[11][2];
    for (int i=0;i<11;i++){
        size_t sz = (size_t)(ws[i].ka + ws[i].kb) * ws[i].n;  // ushorts per plane
        float* blk = alloc(sz);                                // 2 planes
        wp[i][0] = (ushort_t*)blk;
        wp[i][1] = wp[i][0] + sz;
    }
    float* br_e[3]; for (int l=0;l<3;l++) br_e[l] = alloc(2048);
    float* br_d[3]; for (int l=0;l<3;l++) br_d[l] = alloc(2048);

    float* bufraw = alloc((size_t)131*SLOT);     // shifted seq slots [-1..129]
    float* ot     = alloc((size_t)BB*SS*256);
    float* cst    = alloc((size_t)3*SLOT);
    float* hb     = alloc((size_t)6*SLOT);
    float* ctx    = alloc((size_t)SLOT);
    float* ht     = alloc((size_t)BB*256);
    float* hdd1   = alloc((size_t)BB*512);
    float* hdd2   = alloc((size_t)BB*256);
    int*   tok    = (int*)alloc(256);
    int*   bar    = (int*)alloc(64);

    // setup
    hipLaunchKernelGGL(init_misc, dim3(1), dim3(64), 0, stream, bar);
    for (int i=0;i<11;i++){
        int K = ws[i].ka + ws[i].kb;
        hipLaunchKernelGGL(split_w, dim3((K+127)/128, ws[i].n), dim3(128), 0, stream,
                           ws[i].a, ws[i].ka, ws[i].b, ws[i].kb, ws[i].ilv,
                           wp[i][0], wp[i][1], ws[i].n);
    }
    for (int l=0;l<3;l++){
        hipLaunchKernelGGL(repack_b, dim3(8), dim3(256), 0, stream, br_e[l], e_b[l]);
        hipLaunchKernelGGL(repack_b, dim3(8), dim3(256), 0, stream, br_d[l], d_b[l]);
    }

    // encoder (persistent, pipelined)
    EncArgs ea;
    ea.l2 = l2;
    for (int l=0;l<3;l++){ ea.Wh[l]=wp[l][0]; ea.Wm[l]=wp[l][1]; ea.bias[l]=br_e[l]; }
    ea.bufraw = bufraw; ea.cst = cst; ea.bar = bar;
    hipLaunchKernelGGL(enc_persist, dim3(NWG), dim3(256), 0, stream, ea);

    // ot = enc_outs @ fc2^T + fc2_b  ([b][s][256])
    hipLaunchKernelGGL(gk, dim3(4, 512), dim3(256), 0, stream,
        bufraw + SLOT, 512L, (long)SLOT, wp[7][0], wp[7][1], 256, 512,
        fc2_b, ot, (long)SS*256, 256L);

    // decoder (persistent)
    DecArgs da;
    da.emb = emb; da.fc3 = fc3_w;
    for (int i=0;i<7;i++){ da.Wh[i]=wp[3+i==3?3:0][0]; }  // placeholder, set below
    da.Wh[0]=wp[3][0]; da.Wm[0]=wp[3][1]; da.bias[0]=br_d[0];
    da.Wh[1]=wp[4][0]; da.Wm[1]=wp[4][1]; da.bias[1]=br_d[1];
    da.Wh[2]=wp[5][0]; da.Wm[2]=wp[5][1]; da.bias[2]=br_d[2];
    da.Wh[3]=wp[6][0]; da.Wm[3]=wp[6][1]; da.bias[3]=fc1_b;
    da.Wh[4]=wp[8][0]; da.Wm[4]=wp[8][1]; da.bias[4]=b1;
    da.Wh[5]=wp[9][0]; da.Wm[5]=wp[9][1]; da.bias[5]=b2;
    da.Wh[6]=wp[10][0]; da.Wm[6]=wp[10][1]; da.bias[6]=b3;
    da.bufraw = bufraw; da.cst = cst;
    da.h00 = hb;        da.h01 = hb + SLOT;
    da.h10 = hb + 2*SLOT; da.h11 = hb + 3*SLOT;
    da.h20 = hb + 4*SLOT; da.h21 = hb + 5*SLOT;
    da.ctx = ctx; da.ht = ht; da.hdd1 = hdd1; da.hdd2 = hdd2;
    da.ot = ot; da.outp = out; da.tok = tok; da.bar = bar;
    hipLaunchKernelGGL(dec_persist, dim3(NWG), dim3(256), 0, stream, da);
}

// Round 6
// 47780.066 us; speedup vs baseline: 2.1437x; 2.1437x over previous
//
#include <hip/hip_runtime.h>

#define BB 256
#define SS 128
#define FDIM 128
#define HH 512
#define H4 2048
#define TDEC 128
#define SOS_TOK 128
#define NWG 256
#define SLOT 131072   // 256*512 floats

typedef short short8 __attribute__((ext_vector_type(8)));
typedef float f32x4 __attribute__((ext_vector_type(4)));
typedef unsigned short ushort_t;

__device__ __forceinline__ float sigf(float x){ return 1.0f/(1.0f+__expf(-x)); }
__device__ __forceinline__ float tanh_f(float x){ return 1.0f - 2.0f/(__expf(2.0f*x)+1.0f); }

// round-to-nearest-even bf16 2-way split: x ~= hi + mid
__device__ __forceinline__ void split2(float x, unsigned& h, unsigned& m){
    union { float f; unsigned u; } a; a.f = x;
    h = (a.u + 0x7fffu + ((a.u>>16)&1u)) >> 16;
    union { unsigned u; float f; } hf; hf.u = h << 16;
    float r1 = x - hf.f;
    union { float f; unsigned u; } b; b.f = r1;
    m = (b.u + 0x7fffu + ((b.u>>16)&1u)) >> 16;
}

__device__ __forceinline__ void splitw8(float4 v, uint2& H, uint2& M){
    unsigned h0,m0,h1,m1,h2,m2,h3,m3;
    split2(v.x,h0,m0); split2(v.y,h1,m1); split2(v.z,h2,m2); split2(v.w,h3,m3);
    H.x = h0 | (h1<<16); H.y = h2 | (h3<<16);
    M.x = m0 | (m1<<16); M.y = m2 | (m3<<16);
}

// weight split: fp32 [N][K] (opt gate-interleave, opt 2-src K-concat) -> 2 bf16 planes
// k-panel layout [K/32][N][32] with 16B-part XOR swizzle
__global__ void split_w(const float* __restrict__ srcA, int KA,
                        const float* __restrict__ srcB, int KB, int ilv,
                        ushort_t* __restrict__ ph, ushort_t* __restrict__ pm, int N){
    int k = blockIdx.x*128 + threadIdx.x;
    int n = blockIdx.y;
    int K = KA + KB;
    if (k >= K) return;
    int row = ilv ? ((n&3)*512 + (n>>2)) : n;
    float w = (k < KA) ? srcA[(size_t)row*KA + k] : srcB[(size_t)row*KB + (k-KA)];
    unsigned h,m; split2(w,h,m);
    size_t off = (size_t)(k>>5)*((size_t)N*32) + (size_t)n*32
               + ((((k>>3)&3) ^ (n&3))<<3) + (k&7);
    ph[off]=(ushort_t)h; pm[off]=(ushort_t)m;
}

__global__ void repack_b(float* __restrict__ dst, const float* __restrict__ src){
    int id = blockIdx.x*256 + threadIdx.x;
    if (id >= 2048) return;
    int g = id & 3, q = id >> 2;
    dst[id] = src[g*512 + q];
}

__global__ void init_misc(int* bar){ if (threadIdx.x < 2) bar[threadIdx.x] = 0; }

// ---- device-wide barrier: monotonic counter+generation, RELAXED spin (no per-poll
// cache maintenance), single release fence before arrival / acquire fence after ----
__device__ __forceinline__ void gbar(int* bar){
    __syncthreads();
    if (threadIdx.x == 0){
        __builtin_amdgcn_fence(__ATOMIC_RELEASE, "agent");
        int g = __hip_atomic_load(&bar[1], __ATOMIC_RELAXED, __HIP_MEMORY_SCOPE_AGENT);
        int a = __hip_atomic_fetch_add(&bar[0], 1, __ATOMIC_RELAXED, __HIP_MEMORY_SCOPE_AGENT);
        if (a == g*NWG + (NWG-1)){
            __hip_atomic_store(&bar[1], g+1, __ATOMIC_RELAXED, __HIP_MEMORY_SCOPE_AGENT);
        } else {
            while (__hip_atomic_load(&bar[1], __ATOMIC_RELAXED, __HIP_MEMORY_SCOPE_AGENT) <= g)
                __builtin_amdgcn_s_sleep(2);
        }
        __builtin_amdgcn_fence(__ATOMIC_ACQUIRE, "agent");
    }
    __syncthreads();
}

// ---- 64x64 GEMM tile, fp32 via 2-way bf16 split (3 MFMA products) ----
__device__ __forceinline__ void gtile(
    ushort_t (&sA)[2][2][2048], ushort_t (&sW)[2][2][2048],
    int row0, int col0,
    const float* __restrict__ A0, long a0B, long a0T,
    const float* __restrict__ A1, const float* __restrict__ A2,
    const int* __restrict__ tok,
    int kx1, int kx2, int Kc,
    const ushort_t* __restrict__ Wh, const ushort_t* __restrict__ Wm, int Nld,
    const float* __restrict__ bias, int relu, int mode,
    float* __restrict__ out, long oB, long oT,
    float* __restrict__ c_io, float* __restrict__ seqo)
{
    const int tid = threadIdx.x;
    const int nk = Kc >> 5;
    f32x4 acc[2][2];
    acc[0][0]=(f32x4){0.f,0.f,0.f,0.f}; acc[0][1]=(f32x4){0.f,0.f,0.f,0.f};
    acc[1][0]=(f32x4){0.f,0.f,0.f,0.f}; acc[1][1]=(f32x4){0.f,0.f,0.f,0.f};
    const int sr = tid >> 2, q4 = tid & 3;
    const int gr = row0 + sr;
    long ro0;
    if (tok) ro0 = (long)tok[gr & 255] * a0B;
    else     ro0 = (long)(gr & 255)*a0B + (long)(gr >> 8)*a0T;
    const long roh = (long)gr * 512;
    const size_t wbase = (size_t)col0*32 + (size_t)tid*8;
    const int swz = sr & 3;
    const int b0 = sr*32 + (q4 & 1)*4;
    const int p0s = ((q4>>1) ^ swz) << 3;
    const int p1s = ((2 + (q4>>1)) ^ swz) << 3;
    float4 va0, va1; uint4 vw0, vw1;

    auto issue = [&](int kt){
        int kg = kt*32;
        const float* sp; long ro; int kb;
        if (kg < kx1){ sp=A0; ro=ro0; kb=kg; }
        else if (kg < kx2){ sp=A1; ro=roh; kb=kg-kx1; }
        else { sp=A2; ro=roh; kb=kg-kx2; }
        const float* p = sp + ro + kb + q4*4;
        va0 = *(const float4*)p;
        va1 = *(const float4*)(p + 16);
        size_t wi = (size_t)kt*((size_t)Nld*32) + wbase;
        vw0 = *(const uint4*)(Wh + wi);
        vw1 = *(const uint4*)(Wm + wi);
    };
    auto commit = [&](int buf){
        uint2 H,M;
        splitw8(va0,H,M);
        *(uint2*)&sA[buf][0][b0 + p0s] = H;
        *(uint2*)&sA[buf][1][b0 + p0s] = M;
        splitw8(va1,H,M);
        *(uint2*)&sA[buf][0][b0 + p1s] = H;
        *(uint2*)&sA[buf][1][b0 + p1s] = M;
        *(uint4*)&sW[buf][0][tid*8] = vw0;
        *(uint4*)&sW[buf][1][tid*8] = vw1;
    };

    const int wid = tid >> 6, lane = tid & 63;
    const int wy = wid >> 1, wx = wid & 1;
    const int l15 = lane & 15, l4 = lane >> 4;
    const int offA = (wy*32 + l15)*32 + ((l4 ^ (l15&3))<<3);
    const int offB = (wx*32 + l15)*32 + ((l4 ^ (l15&3))<<3);

    auto compute = [&](int buf){
        short8 a0h = *(const short8*)&sA[buf][0][offA];
        short8 a0m = *(const short8*)&sA[buf][1][offA];
        short8 a1h = *(const short8*)&sA[buf][0][offA+512];
        short8 a1m = *(const short8*)&sA[buf][1][offA+512];
        short8 b0h = *(const short8*)&sW[buf][0][offB];
        short8 b0m = *(const short8*)&sW[buf][1][offB];
        short8 b1h = *(const short8*)&sW[buf][0][offB+512];
        short8 b1m = *(const short8*)&sW[buf][1][offB+512];
        acc[0][0] = __builtin_amdgcn_mfma_f32_16x16x32_bf16(a0h,b0h,acc[0][0],0,0,0);
        acc[0][0] = __builtin_amdgcn_mfma_f32_16x16x32_bf16(a0h,b0m,acc[0][0],0,0,0);
        acc[0][0] = __builtin_amdgcn_mfma_f32_16x16x32_bf16(a0m,b0h,acc[0][0],0,0,0);
        acc[0][1] = __builtin_amdgcn_mfma_f32_16x16x32_bf16(a0h,b1h,acc[0][1],0,0,0);
        acc[0][1] = __builtin_amdgcn_mfma_f32_16x16x32_bf16(a0h,b1m,acc[0][1],0,0,0);
        acc[0][1] = __builtin_amdgcn_mfma_f32_16x16x32_bf16(a0m,b1h,acc[0][1],0,0,0);
        acc[1][0] = __builtin_amdgcn_mfma_f32_16x16x32_bf16(a1h,b0h,acc[1][0],0,0,0);
        acc[1][0] = __builtin_amdgcn_mfma_f32_16x16x32_bf16(a1h,b0m,acc[1][0],0,0,0);
        acc[1][0] = __builtin_amdgcn_mfma_f32_16x16x32_bf16(a1m,b0h,acc[1][0],0,0,0);
        acc[1][1] = __builtin_amdgcn_mfma_f32_16x16x32_bf16(a1h,b1h,acc[1][1],0,0,0);
        acc[1][1] = __builtin_amdgcn_mfma_f32_16x16x32_bf16(a1h,b1m,acc[1][1],0,0,0);
        acc[1][1] = __builtin_amdgcn_mfma_f32_16x16x32_bf16(a1m,b1h,acc[1][1],0,0,0);
    };

    issue(0);
    commit(0);
    __syncthreads();
    int buf = 0;
    for (int kt=0; kt<nk; ++kt){
        bool more = (kt+1 < nk);
        if (more) issue(kt+1);
        compute(buf);
        if (more) commit(buf^1);
        __syncthreads();
        buf ^= 1;
    }

    if (mode == 0){
        #pragma unroll
        for (int fa=0; fa<2; fa++){
            #pragma unroll
            for (int fb=0; fb<2; fb++){
                int gc = col0 + wx*32 + fb*16 + l15;
                float bv = bias ? bias[gc] : 0.0f;
                #pragma unroll
                for (int i=0;i<4;i++){
                    int r = row0 + wy*32 + fa*16 + l4*4 + i;
                    float v = acc[fa][fb][i] + bv;
                    if (relu) v = fmaxf(v, 0.0f);
                    out[(size_t)(r&255)*oB + (size_t)(r>>8)*oT + gc] = v;
                }
            }
        }
    } else {
        #pragma unroll
        for (int fa=0; fa<2; fa++){
            #pragma unroll
            for (int fb=0; fb<2; fb++){
                int gc = col0 + wx*32 + fb*16 + l15;
                int q = gc >> 2, g = gc & 3;
                float ab = bias[gc];
                #pragma unroll
                for (int i=0;i<4;i++){
                    int r = row0 + wy*32 + fa*16 + l4*4 + i;
                    float z = acc[fa][fb][i] + ab;
                    float x1 = __shfl_xor(z, 1);
                    float x2 = __shfl_xor(z, 2);
                    float x3 = __shfl_xor(z, 3);
                    float zi = (g==0)?z :(g==1)?x1:(g==2)?x2:x3;
                    float zf = (g==1)?z :(g==0)?x1:(g==3)?x2:x3;
                    float zg = (g==2)?z :(g==3)?x1:(g==0)?x2:x3;
                    float zo = (g==3)?z :(g==2)?x1:(g==1)?x2:x3;
                    float co = c_io[(size_t)r*512 + q];
                    float cn = sigf(zf)*co + sigf(zi)*tanh_f(zg);
                    float hn = sigf(zo)*tanh_f(cn);
                    if (g == 1) c_io[(size_t)r*512 + q] = cn;
                    else if (g == 0) seqo[(size_t)r*512 + q] = hn;
                }
            }
        }
    }
}

// ordinary GEMM kernel (used for ot = enc_outs @ fc2^T + b)
__global__ __launch_bounds__(256) void gk(
    const float* __restrict__ A0, long a0B, long a0T,
    const ushort_t* __restrict__ Wh, const ushort_t* __restrict__ Wm, int Nld, int Kc,
    const float* __restrict__ bias, float* __restrict__ out, long oB, long oT)
{
    __shared__ __align__(16) ushort_t sA[2][2][2048];
    __shared__ __align__(16) ushort_t sW[2][2][2048];
    gtile(sA, sW, blockIdx.y*64, blockIdx.x*64,
          A0, a0B, a0T, nullptr, nullptr, nullptr,
          Kc, Kc, Kc, Wh, Wm, Nld, bias, 0, 0, out, oB, oT, nullptr, nullptr);
}

// ---------------- persistent encoder: 3 layers pipelined across steps ----------------
struct EncArgs {
    const float* l2;
    const ushort_t* Wh[3]; const ushort_t* Wm[3];
    const float* bias[3];
    float* bufraw; float* cst; int* bar;
};

__global__ __launch_bounds__(256) void enc_persist(EncArgs P){
    __shared__ __align__(16) ushort_t sA[2][2][2048];
    __shared__ __align__(16) ushort_t sW[2][2][2048];
    const int wg = blockIdx.x, tid = threadIdx.x;
    {
        float4 z = {0.f,0.f,0.f,0.f};
        int id = wg*256 + tid;
        float4* b4 = (float4*)P.bufraw;
        float4* c4 = (float4*)P.cst;
        for (int i=id; i<3*SLOT/4; i+=65536){ b4[i] = z; c4[i] = z; }
    }
    gbar(P.bar);
    for (int tau=0; tau<130; ++tau){
        int lmin = (tau > 127) ? (tau - 127) : 0;
        int lmax = (tau < 2) ? tau : 2;
        int ntask = (lmax - lmin + 1) * 128;
        for (int task = wg; task < ntask; task += NWG){
            int l = lmin + (task >> 7);
            int s = tau - l;
            int tt = task & 127;
            int row0 = (tt >> 5)*64, col0 = (tt & 31)*64;   // col-panel sharers same XCD
            const float* A0; long a0B; int kx1, Kc;
            if (l == 0){ A0 = P.l2 + (size_t)s*FDIM; a0B = (long)SS*FDIM; kx1 = 128; Kc = 640; }
            else { A0 = P.bufraw + (size_t)(s+3-l+1)*SLOT; a0B = 512; kx1 = 512; Kc = 1024; }
            const float* A1 = P.bufraw + (size_t)(s+1-l+1)*SLOT;   // h_prev
            float* seqo = P.bufraw + (size_t)(s+2-l+1)*SLOT;       // h_out
            float* cio = P.cst + (size_t)l*SLOT;
            gtile(sA, sW, row0, col0,
                  A0, a0B, 0L, A1, nullptr, nullptr,
                  kx1, Kc, Kc,
                  P.Wh[l], P.Wm[l], 2048,
                  P.bias[l], 0, 2,
                  nullptr, 0L, 0L, cio, seqo);
        }
        gbar(P.bar);
    }
}

// ---------------- persistent decoder ----------------
struct DecArgs {
    const float* emb; const float* fc3;
    const ushort_t* Wh[7]; const ushort_t* Wm[7];   // dec0,dec1,dec2,fc1,w1,w2,w3
    const float* bias[7];                            // br_d0..2, fc1_b, b1, b2, b3
    float* bufraw; float* cst;
    float* h00; float* h01; float* h10; float* h11; float* h20; float* h21;
    float* ctx; float* ht; float* hdd1; float* hdd2;
    float* ot; float* outp; int* tok; int* bar;
};

__global__ __launch_bounds__(256) void dec_persist(DecArgs P){
    __shared__ __align__(16) ushort_t sA[2][2][2048];
    __shared__ __align__(16) ushort_t sW[2][2][2048];
    __shared__ float hts[256], f3s[256], wsm[SS];
    const int wg = blockIdx.x, tid = threadIdx.x;
    float* hp[3][2] = {{P.h00,P.h01},{P.h10,P.h11},{P.h20,P.h21}};
    const float* enc = P.bufraw + SLOT;   // slot 0 = enc_outs [s][b][512]
    {
        int id = wg*256 + tid;
        for (int l=0;l<3;l++){
            const float4* src = (const float4*)(P.bufraw + (size_t)(129-l+1)*SLOT);
            float4* dst = (float4*)hp[l][0];
            for (int i=id; i<SLOT/4; i+=65536) dst[i] = src[i];
        }
        float4 z = {0.f,0.f,0.f,0.f};
        float4* c4 = (float4*)P.ctx;
        for (int i=id; i<SLOT/4; i+=65536) c4[i] = z;
        if (id < 256) P.tok[id] = SOS_TOK;
    }
    gbar(P.bar);

    for (int t=0; t<TDEC; ++t){
        const int p = t & 1;
        // P1: LSTM L0  [emb[tok] | ctx | h0_prev], K=1536
        for (int task=wg; task<128; task+=NWG){
            int row0=(task>>5)*64, col0=(task&31)*64;
            gtile(sA,sW,row0,col0, P.emb,512L,0L, P.ctx, hp[0][p], P.tok,
                  512,1024,1536, P.Wh[0],P.Wm[0],2048, P.bias[0],0,2,
                  nullptr,0L,0L, P.cst, hp[0][p^1]);
        }
        gbar(P.bar);
        // P2: LSTM L1 [h0_new | h1_prev], K=1024
        for (int task=wg; task<128; task+=NWG){
            int row0=(task>>5)*64, col0=(task&31)*64;
            gtile(sA,sW,row0,col0, hp[0][p^1],512L,0L, hp[1][p], nullptr, nullptr,
                  512,1024,1024, P.Wh[1],P.Wm[1],2048, P.bias[1],0,2,
                  nullptr,0L,0L, P.cst+SLOT, hp[1][p^1]);
        }
        gbar(P.bar);
        // P3: LSTM L2
        for (int task=wg; task<128; task+=NWG){
            int row0=(task>>5)*64, col0=(task&31)*64;
            gtile(sA,sW,row0,col0, hp[1][p^1],512L,0L, hp[2][p], nullptr, nullptr,
                  512,1024,1024, P.Wh[2],P.Wm[2],2048, P.bias[2],0,2,
                  nullptr,0L,0L, P.cst+2*SLOT, hp[2][p^1]);
        }
        gbar(P.bar);
        // P4: fc1  ht = h2 @ fc1^T + b  (16 tiles)
        for (int task=wg; task<16; task+=NWG){
            int row0=(task>>2)*64, col0=(task&3)*64;
            gtile(sA,sW,row0,col0, hp[2][p^1],512L,0L, nullptr,nullptr,nullptr,
                  512,512,512, P.Wh[3],P.Wm[3],256, P.bias[3],0,0,
                  P.ht,256L,0L, nullptr,nullptr);
        }
        gbar(P.bar);
        // P5: attention -> ctx (WG = batch element)
        {
            int b = wg;
            hts[tid] = P.ht[(size_t)b*256 + tid];
            f3s[tid] = P.fc3[tid];
            __syncthreads();
            int wave = tid >> 6, lane = tid & 63;
            const float* otb = P.ot + (size_t)b*SS*256;
            for (int i=0;i<32;i++){
                int s = wave*32 + i;
                float4 o = *(const float4*)&otb[(size_t)s*256 + lane*4];
                int d0 = lane*4;
                float v = f3s[d0+0]*tanh_f(o.x + hts[d0+0])
                        + f3s[d0+1]*tanh_f(o.y + hts[d0+1])
                        + f3s[d0+2]*tanh_f(o.z + hts[d0+2])
                        + f3s[d0+3]*tanh_f(o.w + hts[d0+3]);
                #pragma unroll
                for (int off=32; off; off>>=1) v += __shfl_xor(v, off);
                if (lane == 0) wsm[s] = v;
            }
            __syncthreads();
            if (tid < 64){
                float v0 = wsm[tid], v1 = wsm[tid+64];
                float m = fmaxf(v0, v1);
                #pragma unroll
                for (int off=32; off; off>>=1) m = fmaxf(m, __shfl_xor(m, off));
                float e0 = __expf(v0 - m), e1 = __expf(v1 - m);
                float ss = e0 + e1;
                #pragma unroll
                for (int off=32; off; off>>=1) ss += __shfl_xor(ss, off);
                float inv = 1.0f/ss;
                wsm[tid] = e0*inv; wsm[tid+64] = e1*inv;
            }
            __syncthreads();
            float a0=0.f, a1=0.f;
            const float* eb = enc + (size_t)b*HH;
            #pragma unroll 8
            for (int s=0;s<SS;s++){
                float w = wsm[s];
                const float* e = eb + (size_t)s*BB*HH;
                a0 = fmaf(w, e[tid],     a0);
                a1 = fmaf(w, e[tid+256], a1);
            }
            P.ctx[(size_t)b*HH + tid]     = a0;
            P.ctx[(size_t)b*HH + tid+256] = a1;
        }
        gbar(P.bar);
        // P6: mlp1 [h2|ctx] @ w1^T + b1, relu (32 tiles)
        for (int task=wg; task<32; task+=NWG){
            int row0=(task>>3)*64, col0=(task&7)*64;
            gtile(sA,sW,row0,col0, hp[2][p^1],512L,0L, P.ctx, nullptr, nullptr,
                  512,1024,1024, P.Wh[4],P.Wm[4],512, P.bias[4],1,0,
                  P.hdd1,512L,0L, nullptr,nullptr);
        }
        gbar(P.bar);
        // P7: mlp2 (16 tiles)
        for (int task=wg; task<16; task+=NWG){
            int row0=(task>>2)*64, col0=(task&3)*64;
            gtile(sA,sW,row0,col0, P.hdd1,512L,0L, nullptr,nullptr,nullptr,
                  512,512,512, P.Wh[5],P.Wm[5],256, P.bias[5],1,0,
                  P.hdd2,256L,0L, nullptr,nullptr);
        }
        gbar(P.bar);
        // P8: mlp3 -> logits + in-WG argmax (4 WGs, each owns 64 rows x 128 cols)
        {
            float* lgp = P.outp + (size_t)t*BB*128;
            for (int task=wg; task<4; task+=NWG){
                int row0 = task*64;
                gtile(sA,sW,row0,0, P.hdd2,256L,0L, nullptr,nullptr,nullptr,
                      256,256,256, P.Wh[6],P.Wm[6],128, P.bias[6],0,0,
                      lgp,128L,0L, nullptr,nullptr);
                gtile(sA,sW,row0,64, P.hdd2,256L,0L, nullptr,nullptr,nullptr,
                      256,256,256, P.Wh[6],P.Wm[6],128, P.bias[6],0,0,
                      lgp,128L,0L, nullptr,nullptr);
                __syncthreads();
                if (tid < 64){
                    int r = row0 + tid;
                    const float* lr_ = lgp + (size_t)r*128;
                    float bv = lr_[0]; int bi = 0;
                    #pragma unroll 4
                    for (int j=1;j<128;j++){ float v = lr_[j]; if (v > bv){ bv = v; bi = j; } }
                    P.tok[r] = bi;
                }
            }
        }
        gbar(P.bar);
    }
}

extern "C" void kernel_launch(void* const* d_in, const int* in_sizes, int n_in,
                              void* d_out, int out_size, void* d_ws, size_t ws_size,
                              hipStream_t stream)
{
    (void)in_sizes; (void)n_in; (void)out_size; (void)ws_size;
    const float* l2      = (const float*)d_in[0];
    const float* e_wih[3] = {(const float*)d_in[1],(const float*)d_in[4],(const float*)d_in[7]};
    const float* e_whh[3] = {(const float*)d_in[2],(const float*)d_in[5],(const float*)d_in[8]};
    const float* e_b[3]   = {(const float*)d_in[3],(const float*)d_in[6],(const float*)d_in[9]};
    const float* d_wih[3] = {(const float*)d_in[10],(const float*)d_in[13],(const float*)d_in[16]};
    const float* d_whh[3] = {(const float*)d_in[11],(const float*)d_in[14],(const float*)d_in[17]};
    const float* d_b[3]   = {(const float*)d_in[12],(const float*)d_in[15],(const float*)d_in[18]};
    const float* emb   = (const float*)d_in[19];
    const float* fc1_w = (const float*)d_in[20]; const float* fc1_b = (const float*)d_in[21];
    const float* fc2_w = (const float*)d_in[22]; const float* fc2_b = (const float*)d_in[23];
    const float* fc3_w = (const float*)d_in[24];
    const float* w1 = (const float*)d_in[25]; const float* b1 = (const float*)d_in[26];
    const float* w2 = (const float*)d_in[27]; const float* b2 = (const float*)d_in[28];
    const float* w3 = (const float*)d_in[29]; const float* b3 = (const float*)d_in[30];
    float* out = (float*)d_out;

    float* base = (float*)d_ws;
    size_t off = 0;
    auto alloc = [&](size_t n)->float*{ float* r = base + off; off = (off + n + 63) & ~(size_t)63; return r; };

    struct WSpec { const float* a; int ka; const float* b; int kb; int ilv; int n; };
    WSpec ws[11] = {
        {e_wih[0],128, e_whh[0],512, 1,2048},
        {e_wih[1],512, e_whh[1],512, 1,2048},
        {e_wih[2],512, e_whh[2],512, 1,2048},
        {d_wih[0],1024, d_whh[0],512, 1,2048},
        {d_wih[1],512, d_whh[1],512, 1,2048},
        {d_wih[2],512, d_whh[2],512, 1,2048},
        {fc1_w,512, nullptr,0, 0,256},
        {fc2_w,512, nullptr,0, 0,256},
        {w1,1024, nullptr,0, 0,512},
        {w2,512, nullptr,0, 0,256},
        {w3,256, nullptr,0, 0,128}
    };
    ushort_t* wp[11][2];
    for (int i=0;i<11;i++){
        size_t sz = (size_t)(ws[i].ka + ws[i].kb) * ws[i].n;
        float* blk = alloc(sz);
        wp[i][0] = (ushort_t*)blk;
        wp[i][1] = wp[i][0] + sz;
    }
    float* br_e[3]; for (int l=0;l<3;l++) br_e[l] = alloc(2048);
    float* br_d[3]; for (int l=0;l<3;l++) br_d[l] = alloc(2048);

    float* bufraw = alloc((size_t)131*SLOT);
    float* ot     = alloc((size_t)BB*SS*256);
    float* cst    = alloc((size_t)3*SLOT);
    float* hb     = alloc((size_t)6*SLOT);
    float* ctx    = alloc((size_t)SLOT);
    float* ht     = alloc((size_t)BB*256);
    float* hdd1   = alloc((size_t)BB*512);
    float* hdd2   = alloc((size_t)BB*256);
    int*   tok    = (int*)alloc(256);
    int*   bar    = (int*)alloc(64);

    hipLaunchKernelGGL(init_misc, dim3(1), dim3(64), 0, stream, bar);
    for (int i=0;i<11;i++){
        int K = ws[i].ka + ws[i].kb;
        hipLaunchKernelGGL(split_w, dim3((K+127)/128, ws[i].n), dim3(128), 0, stream,
                           ws[i].a, ws[i].ka, ws[i].b, ws[i].kb, ws[i].ilv,
                           wp[i][0], wp[i][1], ws[i].n);
    }
    for (int l=0;l<3;l++){
        hipLaunchKernelGGL(repack_b, dim3(8), dim3(256), 0, stream, br_e[l], e_b[l]);
        hipLaunchKernelGGL(repack_b, dim3(8), dim3(256), 0, stream, br_d[l], d_b[l]);
    }

    EncArgs ea;
    ea.l2 = l2;
    for (int l=0;l<3;l++){ ea.Wh[l]=wp[l][0]; ea.Wm[l]=wp[l][1]; ea.bias[l]=br_e[l]; }
    ea.bufraw = bufraw; ea.cst = cst; ea.bar = bar;
    hipLaunchKernelGGL(enc_persist, dim3(NWG), dim3(256), 0, stream, ea);

    hipLaunchKernelGGL(gk, dim3(4, 512), dim3(256), 0, stream,
        bufraw + SLOT, 512L, (long)SLOT, wp[7][0], wp[7][1], 256, 512,
        fc2_b, ot, (long)SS*256, 256L);

    DecArgs da;
    da.emb = emb; da.fc3 = fc3_w;
    da.Wh[0]=wp[3][0]; da.Wm[0]=wp[3][1]; da.bias[0]=br_d[0];
    da.Wh[1]=wp[4][0]; da.Wm[1]=wp[4][1]; da.bias[1]=br_d[1];
    da.Wh[2]=wp[5][0]; da.Wm[2]=wp[5][1]; da.bias[2]=br_d[2];
    da.Wh[3]=wp[6][0]; da.Wm[3]=wp[6][1]; da.bias[3]=fc1_b;
    da.Wh[4]=wp[8][0]; da.Wm[4]=wp[8][1]; da.bias[4]=b1;
    da.Wh[5]=wp[9][0]; da.Wm[5]=wp[9][1]; da.bias[5]=b2;
    da.Wh[6]=wp[10][0]; da.Wm[6]=wp[10][1]; da.bias[6]=b3;
    da.bufraw = bufraw; da.cst = cst;
    da.h00 = hb;          da.h01 = hb + SLOT;
    da.h10 = hb + 2*SLOT; da.h11 = hb + 3*SLOT;
    da.h20 = hb + 4*SLOT; da.h21 = hb + 5*SLOT;
    da.ctx = ctx; da.ht = ht; da.hdd1 = hdd1; da.hdd2 = hdd2;
    da.ot = ot; da.outp = out; da.tok = tok; da.bar = bar;
    hipLaunchKernelGGL(dec_persist, dim3(NWG), dim3(256), 0, stream, da);
}